// Round 1
// baseline (4007.998 us; speedup 1.0000x reference)
//
#include <hip/hip_runtime.h>
#include <math.h>

// Problem constants
#define BB   512
#define NN   200
#define DD   128
#define NEGV (-1e9f)

// ws layout (float offsets):
//   OUT  [B*N][512] : cols 0..127 K1, 128..255 V, 256..383 U=K2@Wout, 384..511 EQ=emb@Wq[:,2:]^T
//   M    [128][512]
//   QR   [B][128]  (rf part of q)
//   QI   [B][128]  (step-0 q, includes init_node)
//   SOL  [B][200]
#define OUT_F   0l
#define M_F     52428800l
#define QR_F    (M_F + 65536l)
#define QI_F    (QR_F + 65536l)
#define SOL_F   (QI_F + 65536l)
#define WS_FLOATS (SOL_F + 102400l)   // 52,727,808 floats = 210,911,232 bytes

__global__ __launch_bounds__(256)
void build_M(const float* __restrict__ Wk1, const float* __restrict__ Wv,
             const float* __restrict__ Wk2, const float* __restrict__ Wout,
             const float* __restrict__ Wq, float* __restrict__ Mbuf) {
  int g = blockIdx.x * 256 + threadIdx.x;   // 65536
  int j = g >> 9, c = g & 511;
  float val;
  if (c < 128) {
    val = Wk1[c * 128 + j];                 // K1[n,d] = sum_j emb[j]*Wk1[d,j]
  } else if (c < 256) {
    val = Wv[(c - 128) * 128 + j];
  } else if (c < 384) {
    int d = c - 256;
    float s = 0.f;
    for (int e = 0; e < 128; ++e) s += Wk2[e * 128 + j] * Wout[e * 128 + d];
    val = s;                                // U[n,d] = sum_e K2[n,e]*Wout[e,d]
  } else {
    val = Wq[(c - 384) * 130 + 2 + j];      // EQ[n,d] = sum_j emb[j]*Wq[d,2+j]
  }
  Mbuf[j * 512 + c] = val;
}

__global__ __launch_bounds__(256)
void build_Q(const float* __restrict__ rf, const float* __restrict__ Wq,
             const float* __restrict__ initn, float* __restrict__ QR,
             float* __restrict__ QI) {
  int g = blockIdx.x * 256 + threadIdx.x;   // 65536 = 512*128
  int b = g >> 7, d = g & 127;
  float qr = Wq[d * 130 + 0] * rf[b * 2 + 0] + Wq[d * 130 + 1] * rf[b * 2 + 1];
  float qi = qr;
  for (int j = 0; j < 128; ++j) qi += Wq[d * 130 + 2 + j] * initn[j];
  QR[g] = qr;
  QI[g] = qi;
}

// OUT[r][c] = sum_j emb[r][j] * M[j][c]  (+ bias for c<128)
// Register-tiled 4x4, no LDS; A-rows and B-panel are L1/L2 resident.
__global__ __launch_bounds__(256)
void gemm_static(const float* __restrict__ emb, const float* __restrict__ Mbuf,
                 const float* __restrict__ bk1, float* __restrict__ OUT) {
  int bid = blockIdx.x;                 // 1600 row-tiles * 8 col-tiles
  int rt = bid >> 3, ct = bid & 7;
  int r0 = rt * 64, c0 = ct * 64;
  int t = threadIdx.x, ty = t >> 4, tx = t & 15;
  int row0 = r0 + ty * 4;
  int col  = c0 + tx * 4;
  float acc[4][4] = {};
  const float* mp = Mbuf + col;
  for (int kb = 0; kb < 32; ++kb) {
    int k = kb * 4;
    float4 b0 = *(const float4*)(mp + (long)(k + 0) * 512);
    float4 b1 = *(const float4*)(mp + (long)(k + 1) * 512);
    float4 b2 = *(const float4*)(mp + (long)(k + 2) * 512);
    float4 b3 = *(const float4*)(mp + (long)(k + 3) * 512);
    float bm[4][4] = {{b0.x,b0.y,b0.z,b0.w},{b1.x,b1.y,b1.z,b1.w},
                      {b2.x,b2.y,b2.z,b2.w},{b3.x,b3.y,b3.z,b3.w}};
    #pragma unroll
    for (int rr = 0; rr < 4; ++rr) {
      float4 a4 = *(const float4*)(emb + (long)(row0 + rr) * 128 + k);
      float av[4] = {a4.x, a4.y, a4.z, a4.w};
      #pragma unroll
      for (int i = 0; i < 4; ++i)
        #pragma unroll
        for (int cc = 0; cc < 4; ++cc)
          acc[rr][cc] += av[i] * bm[i][cc];
    }
  }
  float badd[4] = {0.f, 0.f, 0.f, 0.f};
  if (c0 < 128) {
    #pragma unroll
    for (int cc = 0; cc < 4; ++cc) badd[cc] = bk1[col + cc];
  }
  #pragma unroll
  for (int rr = 0; rr < 4; ++rr) {
    float4 v;
    v.x = acc[rr][0] + badd[0];
    v.y = acc[rr][1] + badd[1];
    v.z = acc[rr][2] + badd[2];
    v.w = acc[rr][3] + badd[3];
    *(float4*)(OUT + (long)(row0 + rr) * 512 + col) = v;
  }
}

// One block per batch element. 1024 threads (16 waves), 1 block/CU.
// K1 in LDS ([d][n], conflict-free), V and U in registers, 200-step loop.
__global__ __launch_bounds__(1024)
void decode(const float* __restrict__ OUT, const float* __restrict__ QR,
            const float* __restrict__ QI, float* __restrict__ sol,
            float* __restrict__ out) {
  __shared__ float k1t[25600];   // [d][n] : k1t[d*200+n]
  __shared__ float at[1600];     // attn [h][n]
  __shared__ float mhal[128];
  __shared__ float lg[200];
  __shared__ float qv[128];
  __shared__ float msk[200];
  __shared__ int   bci[1];

  const int b = blockIdx.x;
  const int t = threadIdx.x;
  const int lane = t & 63;
  const int wave = t >> 6;
  const float* outb = OUT + (long)b * 200 * 512;

  // K1 -> LDS (transpose to [d][n])
  for (int k = 0; k < 25; ++k) {
    int f = k * 1024 + t;
    int n = f >> 7, d = f & 127;
    k1t[d * 200 + n] = outb[n * 512 + d];
  }
  // V -> regs: thread (o = t>>3, q8 = t&7) holds V[n = q8*25+i][o], i<25
  const int o  = t >> 3, q8 = t & 7;
  float vreg[25];
  #pragma unroll
  for (int i = 0; i < 25; ++i) vreg[i] = outb[(q8 * 25 + i) * 512 + 128 + o];
  // U -> regs: thread (m4 = t>>2 < 200, j4 = t&3) holds U[m4][j4*32+i], i<32
  const int m4 = t >> 2, j4 = t & 3;
  float ureg[32];
  if (t < 800) {
    #pragma unroll
    for (int i = 0; i < 32; ++i) ureg[i] = outb[m4 * 512 + 256 + j4 * 32 + i];
  }
  if (t < 200) msk[t] = 0.f;

  bool live = true, picked0 = false;
  int prev = 0;
  float llsum = 0.f;

  for (int st = 0; st < 200; ++st) {
    // ---- Phase Q: q = QR + EQ[prev]  (step 0: QI) ----
    if (t < 128) {
      qv[t] = (st == 0) ? QI[b * 128 + t]
                        : (QR[b * 128 + t] + outb[prev * 512 + 384 + t]);
    }
    __syncthreads();

    // ---- Phase S: scores + softmax, wave w handles head h=w ----
    if (wave < 8) {
      const int h = wave;
      float q16[16];
      #pragma unroll
      for (int d = 0; d < 16; ++d) q16[d] = qv[h * 16 + d];
      float sv[4];
      float vmax = -INFINITY;
      #pragma unroll
      for (int kk = 0; kk < 4; ++kk) {
        int n = lane + 64 * kk;
        float s;
        if (n < 200) {
          float a = 0.f;
          #pragma unroll
          for (int d = 0; d < 16; ++d)
            a += q16[d] * k1t[(h * 16 + d) * 200 + n];
          s = a * 0.25f;                   // / sqrt(16)
          if (msk[n] != 0.f) s = NEGV;
        } else {
          s = -INFINITY;                   // padding: never wins max, exp->0
        }
        sv[kk] = s;
        vmax = fmaxf(vmax, s);
      }
      #pragma unroll
      for (int off = 32; off > 0; off >>= 1)
        vmax = fmaxf(vmax, __shfl_xor(vmax, off));
      float pv[4], lsum = 0.f;
      #pragma unroll
      for (int kk = 0; kk < 4; ++kk) { pv[kk] = expf(sv[kk] - vmax); lsum += pv[kk]; }
      #pragma unroll
      for (int off = 32; off > 0; off >>= 1) lsum += __shfl_xor(lsum, off);
      #pragma unroll
      for (int kk = 0; kk < 4; ++kk) {
        int n = lane + 64 * kk;
        if (n < 200) at[h * 200 + n] = pv[kk] / lsum;
      }
    }
    __syncthreads();

    // ---- Phase M: mha[o] = sum_n attn[h][n] * V[n][o] ----
    {
      const int h2 = t >> 7;
      float a = 0.f;
      #pragma unroll
      for (int i = 0; i < 25; ++i)
        a += at[h2 * 200 + q8 * 25 + i] * vreg[i];
      a += __shfl_xor(a, 1);
      a += __shfl_xor(a, 2);
      a += __shfl_xor(a, 4);
      if (q8 == 0) mhal[o] = a;
    }
    __syncthreads();

    // ---- Phase Z: logits[m] = 10*tanh((mha . U[m]) / sqrt(128)) ----
    if (t < 800) {
      float a = 0.f;
      #pragma unroll
      for (int ii = 0; ii < 32; ++ii) {
        int i = (ii + j4 * 8) & 31;        // rotate start: bank-conflict-free
        a += mhal[j4 * 32 + i] * ureg[i];
      }
      a += __shfl_xor(a, 1);
      a += __shfl_xor(a, 2);
      if (j4 == 0) {
        float z = a / 11.313708498984761f;  // sqrt(128) in f32
        float l = 10.f * tanhf(z);
        lg[m4] = (msk[m4] != 0.f) ? NEGV : l;
      }
    }
    __syncthreads();

    // ---- Phase R: log_softmax + argmax (wave 0) ----
    float chose = 0.f;
    if (wave == 0) {
      float v[4];
      float vmax = -INFINITY;
      #pragma unroll
      for (int kk = 0; kk < 4; ++kk) {
        int n = lane + 64 * kk;
        v[kk] = (n < 200) ? lg[n] : -INFINITY;
        vmax = fmaxf(vmax, v[kk]);
      }
      #pragma unroll
      for (int off = 32; off > 0; off >>= 1)
        vmax = fmaxf(vmax, __shfl_xor(vmax, off));
      float se = 0.f;
      #pragma unroll
      for (int kk = 0; kk < 4; ++kk) se += expf(v[kk] - vmax);
      #pragma unroll
      for (int off = 32; off > 0; off >>= 1) se += __shfl_xor(se, off);
      float lse = logf(se);
      float lp[4];
      float bmax = -INFINITY; int bidx = 0;
      #pragma unroll
      for (int kk = 0; kk < 4; ++kk) {
        int n = lane + 64 * kk;
        lp[kk] = (v[kk] - vmax) - lse;     // same op order as jax log_softmax
        if (n < 200 && lp[kk] > bmax) { bmax = lp[kk]; bidx = n; }
      }
      #pragma unroll
      for (int off = 1; off < 64; off <<= 1) {
        float ov = __shfl_xor(bmax, off);
        int   oi = __shfl_xor(bidx, off);
        if (ov > bmax || (ov == bmax && oi < bidx)) { bmax = ov; bidx = oi; }
      }
      if (lane == 0) {
        int nxt = live ? bidx : 0;
        bci[0] = nxt;
        chose = live ? bmax : lp[0];       // lp[0] = log_p at node 0
        out[2048 + b * 200 + st] = (float)nxt;
      }
    }
    __syncthreads();

    int nxt = bci[0];
    if (!live) {
      // frozen step: all remaining steps are bit-identical
      if (t == 0) llsum += chose * (float)(200 - st);
      for (int s2 = st + 1 + t; s2 < 200; s2 += 1024)
        out[2048 + b * 200 + s2] = 0.f;
      break;
    }
    if (t == 0) { llsum += chose; msk[nxt] = 1.f; }
    prev = nxt;
    if (nxt == 0) { live = false; picked0 = true; }
  }
  __syncthreads();

  if (t == 0) out[1536 + b] = picked0 ? llsum : 0.f;
  if (t < 200) {
    float s = (t == 0) ? 1.f : ((picked0 && msk[t] != 0.f) ? 1.f : 0.f);
    sol[b * 200 + t] = s;
  }
}

// f1,f2,cost per batch.  f = sum_{i in S} sum_j x[b,i,j]*sol[j]
__global__ __launch_bounds__(256)
void cost_kernel(const float* __restrict__ x, const float* __restrict__ rf,
                 const float* __restrict__ sol, float* __restrict__ out) {
  __shared__ float solL[256];
  __shared__ float red[8];
  const int b = blockIdx.x, t = threadIdx.x;
  solL[t] = (t < 200) ? sol[b * 200 + t] : 0.f;
  __syncthreads();
  const float* x0 = x + (long)b * 40000;
  const float* x1 = x + 20480000l + (long)b * 40000;
  float a1 = 0.f, a2 = 0.f;
  if (t < 200) {
    for (int i = 0; i < 200; ++i) {
      if (solL[i] != 0.f) {          // uniform branch
        a1 += x0[i * 200 + t];
        a2 += x1[i * 200 + t];
      }
    }
    float w = solL[t];
    a1 *= w; a2 *= w;
  }
  #pragma unroll
  for (int off = 32; off > 0; off >>= 1) {
    a1 += __shfl_xor(a1, off);
    a2 += __shfl_xor(a2, off);
  }
  if ((t & 63) == 0) { red[(t >> 6) * 2] = a1; red[(t >> 6) * 2 + 1] = a2; }
  __syncthreads();
  if (t == 0) {
    float f1 = red[0] + red[2] + red[4] + red[6];
    float f2 = red[1] + red[3] + red[5] + red[7];
    out[b]        = -(f1 * rf[0] + f2 * rf[1]);   // rf[0,0], rf[0,1]
    out[512 + b]  = f1;
    out[1024 + b] = f2;
  }
}

extern "C" void kernel_launch(void* const* d_in, const int* in_sizes, int n_in,
                              void* d_out, int out_size, void* d_ws, size_t ws_size,
                              hipStream_t stream) {
  const float* x     = (const float*)d_in[0];
  const float* rf    = (const float*)d_in[1];
  const float* emb   = (const float*)d_in[2];
  // d_in[3] = graph_embedding (unused by reference)
  const float* Wk1   = (const float*)d_in[4];
  const float* bk1   = (const float*)d_in[5];
  const float* Wv    = (const float*)d_in[6];
  const float* Wk2   = (const float*)d_in[7];
  const float* Wout  = (const float*)d_in[8];
  const float* Wq    = (const float*)d_in[9];
  const float* initn = (const float*)d_in[10];
  float* out = (float*)d_out;
  float* ws  = (float*)d_ws;

  if (ws_size < (size_t)WS_FLOATS * 4) return;  // need ~211 MB scratch

  float* OUTb = ws + OUT_F;
  float* Mb   = ws + M_F;
  float* QRb  = ws + QR_F;
  float* QIb  = ws + QI_F;
  float* solb = ws + SOL_F;

  build_M<<<256, 256, 0, stream>>>(Wk1, Wv, Wk2, Wout, Wq, Mb);
  build_Q<<<256, 256, 0, stream>>>(rf, Wq, initn, QRb, QIb);
  gemm_static<<<12800, 256, 0, stream>>>(emb, Mb, bk1, OUTb);
  decode<<<512, 1024, 0, stream>>>(OUTb, QRb, QIb, solb, out);
  cost_kernel<<<512, 256, 0, stream>>>(x, rf, solb, out);
}

// Round 3
// 3956.155 us; speedup vs baseline: 1.0131x; 1.0131x over previous
//
#include <hip/hip_runtime.h>
#include <math.h>

#define NEGV (-1e9f)

// ws layout (float offsets):
//   OUT  [B*N][512] : cols 0..127 K1, 128..255 V, 256..383 U=K2@Wout, 384..511 EQ
//   M    [128][512]
//   QR   [B][128]   QI [B][128]
//   SOL  [B][200]
//   TAB  [B][201][8][200]  precomputed scores (p=200 row = step-0 / QI query)
#define OUT_F   0l
#define M_F     52428800l
#define QR_F    (M_F + 65536l)
#define QI_F    (QR_F + 65536l)
#define SOL_F   (QI_F + 65536l)
#define WS_FLOATS (SOL_F + 102400l)      // legacy need: 52,727,808 floats
#define TAB_F   (SOL_F + 102400l)
#define TAB_FLOATS 164659200l            // 512*201*8*200
#define WS_FAST (TAB_F + TAB_FLOATS)     // 217,489,408 floats (~830 MiB)

// ---------------- DPP / cross-lane helpers ----------------
#define DPPF(x, ctrl, oldv) __int_as_float(__builtin_amdgcn_update_dpp( \
      __float_as_int(oldv), __float_as_int(x), ctrl, 0xF, 0xF, false))

// full-wave max (exact regardless of order), broadcast via readlane 63
__device__ __forceinline__ float wave_max(float x) {
  x = fmaxf(x, DPPF(x, 0x111, -INFINITY));   // row_shr:1
  x = fmaxf(x, DPPF(x, 0x112, -INFINITY));   // row_shr:2
  x = fmaxf(x, DPPF(x, 0x114, -INFINITY));   // row_shr:4
  x = fmaxf(x, DPPF(x, 0x118, -INFINITY));   // row_shr:8
  x = fmaxf(x, DPPF(x, 0x142, -INFINITY));   // row_bcast:15
  x = fmaxf(x, DPPF(x, 0x143, -INFINITY));   // row_bcast:31
  return __int_as_float(__builtin_amdgcn_readlane(__float_as_int(x), 63));
}
// full-wave sum, order-free (used only where ulp drift is harmless for
// DECISIONS; lse ulp matches argmax path exactly since it shifts all lp equally)
__device__ __forceinline__ float wave_sum_any(float x) {
  x = x + DPPF(x, 0x111, 0.f);
  x = x + DPPF(x, 0x112, 0.f);
  x = x + DPPF(x, 0x114, 0.f);
  x = x + DPPF(x, 0x118, 0.f);
  x = x + DPPF(x, 0x142, 0.f);
  x = x + DPPF(x, 0x143, 0.f);
  return __int_as_float(__builtin_amdgcn_readlane(__float_as_int(x), 63));
}
// exact descending xor-butterfly (bit-identical to round-1's shfl_xor 32..1)
__device__ __forceinline__ float bfly_sum_desc(float x) {
  x += __shfl_xor(x, 32);
  x += __shfl_xor(x, 16);
  x += __int_as_float(__builtin_amdgcn_ds_swizzle(__float_as_int(x), 0x201F)); // ^8
  x += __int_as_float(__builtin_amdgcn_ds_swizzle(__float_as_int(x), 0x101F)); // ^4
  x += DPPF(x, 0x4E, 0.f);   // ^2 quad_perm [2,3,0,1]
  x += DPPF(x, 0xB1, 0.f);   // ^1 quad_perm [1,0,3,2]
  return x;
}

// ---------------- static precompute kernels ----------------
__global__ __launch_bounds__(256)
void build_M(const float* __restrict__ Wk1, const float* __restrict__ Wv,
             const float* __restrict__ Wk2, const float* __restrict__ Wout,
             const float* __restrict__ Wq, float* __restrict__ Mbuf) {
  int g = blockIdx.x * 256 + threadIdx.x;
  int j = g >> 9, c = g & 511;
  float val;
  if (c < 128) {
    val = Wk1[c * 128 + j];
  } else if (c < 256) {
    val = Wv[(c - 128) * 128 + j];
  } else if (c < 384) {
    int d = c - 256;
    float s = 0.f;
    for (int e = 0; e < 128; ++e) s += Wk2[e * 128 + j] * Wout[e * 128 + d];
    val = s;
  } else {
    val = Wq[(c - 384) * 130 + 2 + j];
  }
  Mbuf[j * 512 + c] = val;
}

__global__ __launch_bounds__(256)
void build_Q(const float* __restrict__ rf, const float* __restrict__ Wq,
             const float* __restrict__ initn, float* __restrict__ QR,
             float* __restrict__ QI) {
  int g = blockIdx.x * 256 + threadIdx.x;
  int b = g >> 7, d = g & 127;
  float qr = Wq[d * 130 + 0] * rf[b * 2 + 0] + Wq[d * 130 + 1] * rf[b * 2 + 1];
  float qi = qr;
  for (int j = 0; j < 128; ++j) qi += Wq[d * 130 + 2 + j] * initn[j];
  QR[g] = qr;
  QI[g] = qi;
}

__global__ __launch_bounds__(256)
void gemm_static(const float* __restrict__ emb, const float* __restrict__ Mbuf,
                 const float* __restrict__ bk1, float* __restrict__ OUT) {
  int bid = blockIdx.x;
  int rt = bid >> 3, ct = bid & 7;
  int r0 = rt * 64, c0 = ct * 64;
  int t = threadIdx.x, ty = t >> 4, tx = t & 15;
  int row0 = r0 + ty * 4;
  int col  = c0 + tx * 4;
  float acc[4][4] = {};
  const float* mp = Mbuf + col;
  for (int kb = 0; kb < 32; ++kb) {
    int k = kb * 4;
    float4 b0 = *(const float4*)(mp + (long)(k + 0) * 512);
    float4 b1 = *(const float4*)(mp + (long)(k + 1) * 512);
    float4 b2 = *(const float4*)(mp + (long)(k + 2) * 512);
    float4 b3 = *(const float4*)(mp + (long)(k + 3) * 512);
    float bm[4][4] = {{b0.x,b0.y,b0.z,b0.w},{b1.x,b1.y,b1.z,b1.w},
                      {b2.x,b2.y,b2.z,b2.w},{b3.x,b3.y,b3.z,b3.w}};
    #pragma unroll
    for (int rr = 0; rr < 4; ++rr) {
      float4 a4 = *(const float4*)(emb + (long)(row0 + rr) * 128 + k);
      float av[4] = {a4.x, a4.y, a4.z, a4.w};
      #pragma unroll
      for (int i = 0; i < 4; ++i)
        #pragma unroll
        for (int cc = 0; cc < 4; ++cc)
          acc[rr][cc] += av[i] * bm[i][cc];
    }
  }
  float badd[4] = {0.f, 0.f, 0.f, 0.f};
  if (c0 < 128) {
    #pragma unroll
    for (int cc = 0; cc < 4; ++cc) badd[cc] = bk1[col + cc];
  }
  #pragma unroll
  for (int rr = 0; rr < 4; ++rr) {
    float4 v;
    v.x = acc[rr][0] + badd[0];
    v.y = acc[rr][1] + badd[1];
    v.z = acc[rr][2] + badd[2];
    v.w = acc[rr][3] + badd[3];
    *(float4*)(OUT + (long)(row0 + rr) * 512 + col) = v;
  }
}

// scores table: TAB[b][p][h][n] = 0.25 * sum_d (QR[b,hd]+EQ[b,p,hd]) * K1[b,n,hd]
// p==200 row uses QI (step-0 query).  Same dot order as the per-step path.
__global__ __launch_bounds__(256)
void score_table(const float* __restrict__ OUT, const float* __restrict__ QR,
                 const float* __restrict__ QI, float* __restrict__ TAB) {
  __shared__ float k1[200 * 17];   // [n][d] pad 17 -> conflict-free
  __shared__ float qq[201 * 16];   // [p][d]
  const int bid = blockIdx.x;
  const int b = bid >> 3, h = bid & 7;
  const int t = threadIdx.x;
  for (int f = t; f < 3200; f += 256) {
    int n = f >> 4, d = f & 15;
    k1[n * 17 + d] = OUT[((long)(b * 200 + n)) * 512 + h * 16 + d];
  }
  for (int f = t; f < 3216; f += 256) {
    int p = f >> 4, d = f & 15;
    float v;
    if (p < 200)
      v = QR[b * 128 + h * 16 + d] +
          OUT[((long)(b * 200 + p)) * 512 + 384 + h * 16 + d];
    else
      v = QI[b * 128 + h * 16 + d];
    qq[p * 16 + d] = v;
  }
  __syncthreads();
  if (t < 200) {
    float* op = TAB + (((long)b * 201) * 8 + h) * 200 + t;
    for (int p = 0; p < 201; ++p) {
      float a = 0.f;
      #pragma unroll
      for (int d = 0; d < 16; ++d) a += qq[p * 16 + d] * k1[t * 17 + d];
      op[(long)p * 1600] = a * 0.25f;
    }
  }
}

// ---------------- fast decode: table-driven, DPP reductions ----------------
__global__ __launch_bounds__(1024)
void decode_fast(const float* __restrict__ OUT, const float* __restrict__ TAB,
                 float* __restrict__ sol, float* __restrict__ out) {
  __shared__ float at[1600];
  __shared__ float mhal[128];
  __shared__ float lg[200];
  __shared__ int bci;

  const int b = blockIdx.x, t = threadIdx.x;
  const int lane = t & 63, wave = t >> 6;
  const int o = t >> 3, q8 = t & 7;
  const int m4 = t >> 2, j4 = t & 3;
  const float* outb = OUT + (long)b * 200 * 512;
  const float* tabb = TAB + (long)b * 201 * 1600;

  // V in regs: thread (o, q8) holds V[q8*25+i][o]
  float vreg[25];
  #pragma unroll
  for (int i = 0; i < 25; ++i) vreg[i] = outb[(q8 * 25 + i) * 512 + 128 + o];
  // U in regs, pre-rotated so ALL indices are compile-time (no scratch):
  // ureg[ii] = U[m4][j4*32 + ((ii + j4*8)&31)]
  float ureg[32];
  if (t < 800) {
    #pragma unroll
    for (int ii = 0; ii < 32; ++ii) {
      int i = (ii + j4 * 8) & 31;
      ureg[ii] = outb[m4 * 512 + 256 + j4 * 32 + i];
    }
  }
  // prefetch step-0 score row (p = 200)
  float se[4];
  if (wave < 8) {
    const float* rp = tabb + 200l * 1600 + wave * 200;
    #pragma unroll
    for (int k = 0; k < 4; ++k) {
      int n = lane + 64 * k;
      se[k] = (n < 200) ? rp[n] : -INFINITY;
    }
  }
  int mk = 0;        // per-lane mask bits over k (waves 0-7)
  bool cm = false;   // mask flag for node m4 (threads < 800)
  bool live = true, picked0 = false;
  float llsum = 0.f, chose = 0.f;

  __syncthreads();

  for (int st = 0; st < 200; ++st) {
    // ---- A: softmax over prefetched scores (waves 0-7; head = wave) ----
    if (wave < 8) {
      float mx = -INFINITY;
      #pragma unroll
      for (int k = 0; k < 4; ++k) {
        int n = lane + 64 * k;
        float s = se[k];
        if (n < 200 && (mk & (1 << k))) s = NEGV;
        se[k] = s;
        mx = fmaxf(mx, s);
      }
      float vmax = wave_max(mx);
      float ls = 0.f;
      #pragma unroll
      for (int k = 0; k < 4; ++k) { se[k] = expf(se[k] - vmax); ls += se[k]; }
      ls = bfly_sum_desc(ls);          // exact round-1 summation tree
      #pragma unroll
      for (int k = 0; k < 4; ++k) {
        int n = lane + 64 * k;
        if (n < 200) at[wave * 200 + n] = se[k] / ls;
      }
    }
    __syncthreads();

    // ---- B: mha[o] = sum_n attn[h][n] * V[n][o] ----
    {
      const int h2 = t >> 7;
      float a = 0.f;
      #pragma unroll
      for (int i = 0; i < 25; ++i) a += at[h2 * 200 + q8 * 25 + i] * vreg[i];
      a += __shfl_xor(a, 1);
      a += __shfl_xor(a, 2);
      a += __shfl_xor(a, 4);
      if (q8 == 0) mhal[o] = a;
    }
    __syncthreads();

    // ---- C: logits[m] = 10*tanh((mha . U[m]) / sqrt(128)) ----
    if (t < 800) {
      float a = 0.f;
      #pragma unroll
      for (int ii = 0; ii < 32; ++ii) {
        int i = (ii + j4 * 8) & 31;
        a += mhal[j4 * 32 + i] * ureg[ii];
      }
      a += __shfl_xor(a, 1);
      a += __shfl_xor(a, 2);
      if (j4 == 0) {
        float z = a / 11.313708498984761f;
        float l = 10.f * tanhf(z);
        lg[m4] = cm ? NEGV : l;
      }
    }
    __syncthreads();

    // ---- D: argmax + lse + prefetch next row (waves 0-7, redundant) ----
    if (wave < 8) {
      float mx = -INFINITY;
      #pragma unroll
      for (int k = 0; k < 4; ++k) {
        int n = lane + 64 * k;
        float lv = (n < 200) ? lg[n] : -INFINITY;
        mx = fmaxf(mx, lv);
      }
      float vmax = wave_max(mx);
      int bidx = -1;
      #pragma unroll
      for (int k = 0; k < 4; ++k) {
        int n = lane + 64 * k;
        unsigned long long bm = __ballot((n < 200) && (lg[n] == vmax));
        if (bidx < 0 && bm != 0ull) bidx = k * 64 + (int)__builtin_ctzll(bm);
      }
      float e = 0.f;
      #pragma unroll
      for (int k = 0; k < 4; ++k) {
        int n = lane + 64 * k;
        float lv = (n < 200) ? lg[n] : -INFINITY;
        e += expf(lv - vmax);
      }
      float se_ = wave_sum_any(e);
      float lse = logf(se_);
      int nxt = live ? bidx : 0;
      // prefetch the next score row (overlaps lse/stores/barrier)
      const float* rp = tabb + (long)nxt * 1600 + wave * 200;
      #pragma unroll
      for (int k = 0; k < 4; ++k) {
        int n = lane + 64 * k;
        se[k] = (n < 200) ? rp[n] : -INFINITY;
      }
      if (t == 0) {
        chose = live ? (-lse) : ((lg[0] - vmax) - lse);
        out[2048 + (long)b * 200 + st] = (float)nxt;
        bci = nxt;
      }
    }
    __syncthreads();

    int nxt = bci;
    if (!live) {
      if (t == 0) llsum += chose * (float)(200 - st);
      for (int s2 = st + 1 + t; s2 < 200; s2 += 1024)
        out[2048 + (long)b * 200 + s2] = 0.f;
      break;
    }
    if (t == 0) llsum += chose;
    if (wave < 8 && (nxt & 63) == lane) mk |= 1 << (nxt >> 6);
    if (t < 800 && nxt == m4) cm = true;
    if (nxt == 0) { live = false; picked0 = true; }
  }

  if (t == 0) out[1536 + b] = picked0 ? llsum : 0.f;
  if (t < 800 && j4 == 0) {
    float s = (m4 == 0) ? 1.f : ((picked0 && cm) ? 1.f : 0.f);
    sol[(long)b * 200 + m4] = s;
  }
}

// ---------------- legacy decode (round-1, known-pass fallback) ----------------
__global__ __launch_bounds__(1024)
void decode_legacy(const float* __restrict__ OUT, const float* __restrict__ QR,
                   const float* __restrict__ QI, float* __restrict__ sol,
                   float* __restrict__ out) {
  __shared__ float k1t[25600];
  __shared__ float at[1600];
  __shared__ float mhal[128];
  __shared__ float lg[200];
  __shared__ float qv[128];
  __shared__ float msk[200];
  __shared__ int   bcq[1];

  const int b = blockIdx.x;
  const int t = threadIdx.x;
  const int lane = t & 63;
  const int wave = t >> 6;
  const float* outb = OUT + (long)b * 200 * 512;

  for (int k = 0; k < 25; ++k) {
    int f = k * 1024 + t;
    int n = f >> 7, d = f & 127;
    k1t[d * 200 + n] = outb[n * 512 + d];
  }
  const int o  = t >> 3, q8 = t & 7;
  float vreg[25];
  #pragma unroll
  for (int i = 0; i < 25; ++i) vreg[i] = outb[(q8 * 25 + i) * 512 + 128 + o];
  const int m4 = t >> 2, j4 = t & 3;
  float ureg[32];
  if (t < 800) {
    #pragma unroll
    for (int i = 0; i < 32; ++i) ureg[i] = outb[m4 * 512 + 256 + j4 * 32 + i];
  }
  if (t < 200) msk[t] = 0.f;

  bool live = true, picked0 = false;
  int prev = 0;
  float llsum = 0.f;

  for (int st = 0; st < 200; ++st) {
    if (t < 128) {
      qv[t] = (st == 0) ? QI[b * 128 + t]
                        : (QR[b * 128 + t] + outb[prev * 512 + 384 + t]);
    }
    __syncthreads();
    if (wave < 8) {
      const int h = wave;
      float q16[16];
      #pragma unroll
      for (int d = 0; d < 16; ++d) q16[d] = qv[h * 16 + d];
      float sv[4];
      float vmax = -INFINITY;
      #pragma unroll
      for (int kk = 0; kk < 4; ++kk) {
        int n = lane + 64 * kk;
        float s;
        if (n < 200) {
          float a = 0.f;
          #pragma unroll
          for (int d = 0; d < 16; ++d)
            a += q16[d] * k1t[(h * 16 + d) * 200 + n];
          s = a * 0.25f;
          if (msk[n] != 0.f) s = NEGV;
        } else {
          s = -INFINITY;
        }
        sv[kk] = s;
        vmax = fmaxf(vmax, s);
      }
      #pragma unroll
      for (int off = 32; off > 0; off >>= 1)
        vmax = fmaxf(vmax, __shfl_xor(vmax, off));
      float pv[4], lsum = 0.f;
      #pragma unroll
      for (int kk = 0; kk < 4; ++kk) { pv[kk] = expf(sv[kk] - vmax); lsum += pv[kk]; }
      #pragma unroll
      for (int off = 32; off > 0; off >>= 1) lsum += __shfl_xor(lsum, off);
      #pragma unroll
      for (int kk = 0; kk < 4; ++kk) {
        int n = lane + 64 * kk;
        if (n < 200) at[h * 200 + n] = pv[kk] / lsum;
      }
    }
    __syncthreads();
    {
      const int h2 = t >> 7;
      float a = 0.f;
      #pragma unroll
      for (int i = 0; i < 25; ++i)
        a += at[h2 * 200 + q8 * 25 + i] * vreg[i];
      a += __shfl_xor(a, 1);
      a += __shfl_xor(a, 2);
      a += __shfl_xor(a, 4);
      if (q8 == 0) mhal[o] = a;
    }
    __syncthreads();
    if (t < 800) {
      float a = 0.f;
      #pragma unroll
      for (int ii = 0; ii < 32; ++ii) {
        int i = (ii + j4 * 8) & 31;
        a += mhal[j4 * 32 + i] * ureg[i];
      }
      a += __shfl_xor(a, 1);
      a += __shfl_xor(a, 2);
      if (j4 == 0) {
        float z = a / 11.313708498984761f;
        float l = 10.f * tanhf(z);
        lg[m4] = (msk[m4] != 0.f) ? NEGV : l;
      }
    }
    __syncthreads();
    float chose = 0.f;
    if (wave == 0) {
      float v[4];
      float vmax = -INFINITY;
      #pragma unroll
      for (int kk = 0; kk < 4; ++kk) {
        int n = lane + 64 * kk;
        v[kk] = (n < 200) ? lg[n] : -INFINITY;
        vmax = fmaxf(vmax, v[kk]);
      }
      #pragma unroll
      for (int off = 32; off > 0; off >>= 1)
        vmax = fmaxf(vmax, __shfl_xor(vmax, off));
      float se = 0.f;
      #pragma unroll
      for (int kk = 0; kk < 4; ++kk) se += expf(v[kk] - vmax);
      #pragma unroll
      for (int off = 32; off > 0; off >>= 1) se += __shfl_xor(se, off);
      float lse = logf(se);
      float lp[4];
      float bmax = -INFINITY; int bidx = 0;
      #pragma unroll
      for (int kk = 0; kk < 4; ++kk) {
        int n = lane + 64 * kk;
        lp[kk] = (v[kk] - vmax) - lse;
        if (n < 200 && lp[kk] > bmax) { bmax = lp[kk]; bidx = n; }
      }
      #pragma unroll
      for (int off = 1; off < 64; off <<= 1) {
        float ov = __shfl_xor(bmax, off);
        int   oi = __shfl_xor(bidx, off);
        if (ov > bmax || (ov == bmax && oi < bidx)) { bmax = ov; bidx = oi; }
      }
      if (lane == 0) {
        int nxt = live ? bidx : 0;
        bcq[0] = nxt;
        chose = live ? bmax : lp[0];
        out[2048 + b * 200 + st] = (float)nxt;
      }
    }
    __syncthreads();

    int nxt = bcq[0];
    if (!live) {
      if (t == 0) llsum += chose * (float)(200 - st);
      for (int s2 = st + 1 + t; s2 < 200; s2 += 1024)
        out[2048 + b * 200 + s2] = 0.f;
      break;
    }
    if (t == 0) { llsum += chose; msk[nxt] = 1.f; }
    prev = nxt;
    if (nxt == 0) { live = false; picked0 = true; }
  }
  __syncthreads();

  if (t == 0) out[1536 + b] = picked0 ? llsum : 0.f;
  if (t < 200) {
    float s = (t == 0) ? 1.f : ((picked0 && msk[t] != 0.f) ? 1.f : 0.f);
    sol[b * 200 + t] = s;
  }
}

// ---------------- cost ----------------
__global__ __launch_bounds__(256)
void cost_kernel(const float* __restrict__ x, const float* __restrict__ rf,
                 const float* __restrict__ sol, float* __restrict__ out) {
  __shared__ float solL[256];
  __shared__ float red[8];
  const int b = blockIdx.x, t = threadIdx.x;
  solL[t] = (t < 200) ? sol[b * 200 + t] : 0.f;
  __syncthreads();
  const float* x0 = x + (long)b * 40000;
  const float* x1 = x + 20480000l + (long)b * 40000;
  float a1 = 0.f, a2 = 0.f;
  if (t < 200) {
    for (int i = 0; i < 200; ++i) {
      if (solL[i] != 0.f) {
        a1 += x0[i * 200 + t];
        a2 += x1[i * 200 + t];
      }
    }
    float w = solL[t];
    a1 *= w; a2 *= w;
  }
  #pragma unroll
  for (int off = 32; off > 0; off >>= 1) {
    a1 += __shfl_xor(a1, off);
    a2 += __shfl_xor(a2, off);
  }
  if ((t & 63) == 0) { red[(t >> 6) * 2] = a1; red[(t >> 6) * 2 + 1] = a2; }
  __syncthreads();
  if (t == 0) {
    float f1 = red[0] + red[2] + red[4] + red[6];
    float f2 = red[1] + red[3] + red[5] + red[7];
    out[b]        = -(f1 * rf[0] + f2 * rf[1]);
    out[512 + b]  = f1;
    out[1024 + b] = f2;
  }
}

extern "C" void kernel_launch(void* const* d_in, const int* in_sizes, int n_in,
                              void* d_out, int out_size, void* d_ws, size_t ws_size,
                              hipStream_t stream) {
  const float* x     = (const float*)d_in[0];
  const float* rf    = (const float*)d_in[1];
  const float* emb   = (const float*)d_in[2];
  const float* Wk1   = (const float*)d_in[4];
  const float* bk1   = (const float*)d_in[5];
  const float* Wv    = (const float*)d_in[6];
  const float* Wk2   = (const float*)d_in[7];
  const float* Wout  = (const float*)d_in[8];
  const float* Wq    = (const float*)d_in[9];
  const float* initn = (const float*)d_in[10];
  float* out = (float*)d_out;
  float* ws  = (float*)d_ws;

  if (ws_size < (size_t)WS_FLOATS * 4) return;

  float* OUTb = ws + OUT_F;
  float* Mb   = ws + M_F;
  float* QRb  = ws + QR_F;
  float* QIb  = ws + QI_F;
  float* solb = ws + SOL_F;

  build_M<<<256, 256, 0, stream>>>(Wk1, Wv, Wk2, Wout, Wq, Mb);
  build_Q<<<256, 256, 0, stream>>>(rf, Wq, initn, QRb, QIb);
  gemm_static<<<12800, 256, 0, stream>>>(emb, Mb, bk1, OUTb);

  if (ws_size >= (size_t)WS_FAST * 4) {
    float* TABb = ws + TAB_F;
    score_table<<<4096, 256, 0, stream>>>(OUTb, QRb, QIb, TABb);
    decode_fast<<<512, 1024, 0, stream>>>(OUTb, TABb, solb, out);
  } else {
    decode_legacy<<<512, 1024, 0, stream>>>(OUTb, QRb, QIb, solb, out);
  }
  cost_kernel<<<512, 256, 0, stream>>>(x, rf, solb, out);
}

// Round 4
// 2803.999 us; speedup vs baseline: 1.4294x; 1.4109x over previous
//
#include <hip/hip_runtime.h>
#include <math.h>

#define NEGV (-1e9f)

// ws layout (float offsets):
//   OUT [B*N][512] : cols 0..127 K1, 128..255 V, 256..383 U=K2@Wout,
//                    384..511 Qfull = QR + emb@Wq[:,2:]^T  (QR folded in GEMM)
//   M   [128][512], QR [B][128], QI [B][128], SOL [B][200]
#define OUT_F   0l
#define M_F     52428800l
#define QR_F    (M_F + 65536l)
#define QI_F    (QR_F + 65536l)
#define SOL_F   (QI_F + 65536l)
#define WS_FLOATS (SOL_F + 102400l)   // 52,727,808 floats = ~211 MB (known OK)

// ---------------- DPP cross-lane helpers ----------------
#define DPPF(x, ctrl, oldv) __int_as_float(__builtin_amdgcn_update_dpp( \
      __float_as_int(oldv), __float_as_int(x), ctrl, 0xF, 0xF, false))

// full-wave max, exact (order-free), broadcast via readlane 63
__device__ __forceinline__ float wave_max(float x) {
  x = fmaxf(x, DPPF(x, 0x111, -INFINITY));   // row_shr:1
  x = fmaxf(x, DPPF(x, 0x112, -INFINITY));   // row_shr:2
  x = fmaxf(x, DPPF(x, 0x114, -INFINITY));   // row_shr:4
  x = fmaxf(x, DPPF(x, 0x118, -INFINITY));   // row_shr:8
  x = fmaxf(x, DPPF(x, 0x142, -INFINITY));   // row_bcast:15
  x = fmaxf(x, DPPF(x, 0x143, -INFINITY));   // row_bcast:31
  return __int_as_float(__builtin_amdgcn_readlane(__float_as_int(x), 63));
}
// full-wave sum (reassociated; decisions robust per round-1 evidence)
__device__ __forceinline__ float wave_sum(float x) {
  x = x + DPPF(x, 0x111, 0.f);
  x = x + DPPF(x, 0x112, 0.f);
  x = x + DPPF(x, 0x114, 0.f);
  x = x + DPPF(x, 0x118, 0.f);
  x = x + DPPF(x, 0x142, 0.f);
  x = x + DPPF(x, 0x143, 0.f);
  return __int_as_float(__builtin_amdgcn_readlane(__float_as_int(x), 63));
}

// ---------------- static precompute ----------------
__global__ __launch_bounds__(256)
void build_M(const float* __restrict__ Wk1, const float* __restrict__ Wv,
             const float* __restrict__ Wk2, const float* __restrict__ Wout,
             const float* __restrict__ Wq, float* __restrict__ Mbuf) {
  int g = blockIdx.x * 256 + threadIdx.x;
  int j = g >> 9, c = g & 511;
  float val;
  if (c < 128) {
    val = Wk1[c * 128 + j];
  } else if (c < 256) {
    val = Wv[(c - 128) * 128 + j];
  } else if (c < 384) {
    int d = c - 256;
    float s = 0.f;
    for (int e = 0; e < 128; ++e) s += Wk2[e * 128 + j] * Wout[e * 128 + d];
    val = s;
  } else {
    val = Wq[(c - 384) * 130 + 2 + j];
  }
  Mbuf[j * 512 + c] = val;
}

__global__ __launch_bounds__(256)
void build_Q(const float* __restrict__ rf, const float* __restrict__ Wq,
             const float* __restrict__ initn, float* __restrict__ QR,
             float* __restrict__ QI) {
  int g = blockIdx.x * 256 + threadIdx.x;   // 65536 = 512*128
  int b = g >> 7, d = g & 127;
  float qr = Wq[d * 130 + 0] * rf[b * 2 + 0] + Wq[d * 130 + 1] * rf[b * 2 + 1];
  float qi = qr;
  for (int j = 0; j < 128; ++j) qi += Wq[d * 130 + 2 + j] * initn[j];
  QR[g] = qr;
  QI[g] = qi;
}

// OUT[r][c] = emb[r]·M[:,c] (+bias c<128; +QR[b] for c>=384 -> full q rows)
__global__ __launch_bounds__(256)
void gemm_static(const float* __restrict__ emb, const float* __restrict__ Mbuf,
                 const float* __restrict__ bk1, const float* __restrict__ QR,
                 float* __restrict__ OUT) {
  int bid = blockIdx.x;                 // 1600 row-tiles * 8 col-tiles
  int rt = bid >> 3, ct = bid & 7;
  int r0 = rt * 64, c0 = ct * 64;
  int t = threadIdx.x, ty = t >> 4, tx = t & 15;
  int row0 = r0 + ty * 4;
  int col  = c0 + tx * 4;
  float acc[4][4] = {};
  const float* mp = Mbuf + col;
  for (int kb = 0; kb < 32; ++kb) {
    int k = kb * 4;
    float4 b0 = *(const float4*)(mp + (long)(k + 0) * 512);
    float4 b1 = *(const float4*)(mp + (long)(k + 1) * 512);
    float4 b2 = *(const float4*)(mp + (long)(k + 2) * 512);
    float4 b3 = *(const float4*)(mp + (long)(k + 3) * 512);
    float bm[4][4] = {{b0.x,b0.y,b0.z,b0.w},{b1.x,b1.y,b1.z,b1.w},
                      {b2.x,b2.y,b2.z,b2.w},{b3.x,b3.y,b3.z,b3.w}};
    #pragma unroll
    for (int rr = 0; rr < 4; ++rr) {
      float4 a4 = *(const float4*)(emb + (long)(row0 + rr) * 128 + k);
      float av[4] = {a4.x, a4.y, a4.z, a4.w};
      #pragma unroll
      for (int i = 0; i < 4; ++i)
        #pragma unroll
        for (int cc = 0; cc < 4; ++cc)
          acc[rr][cc] += av[i] * bm[i][cc];
    }
  }
  float badd[4] = {0.f, 0.f, 0.f, 0.f};
  if (c0 < 128) {
    #pragma unroll
    for (int cc = 0; cc < 4; ++cc) badd[cc] = bk1[col + cc];
  }
  #pragma unroll
  for (int rr = 0; rr < 4; ++rr) {
    int row = row0 + rr;
    float v[4];
    #pragma unroll
    for (int cc = 0; cc < 4; ++cc) v[cc] = acc[rr][cc] + badd[cc];
    if (col >= 384) {                   // fold QR -> full q rows
      int bb = row / 200;
      #pragma unroll
      for (int cc = 0; cc < 4; ++cc) v[cc] += QR[bb * 128 + (col - 384) + cc];
    }
    float4 v4; v4.x = v[0]; v4.y = v[1]; v4.z = v[2]; v4.w = v[3];
    *(float4*)(OUT + (long)row * 512 + col) = v4;
  }
}

// ---------------- decode: 1 block/batch, 4 barriers/step, no spills ----------------
__global__ __launch_bounds__(1024, 4)   // min 4 waves/SIMD = 1 block/CU -> 128 VGPR
void decode(const float* __restrict__ OUT, const float* __restrict__ QI,
            float* __restrict__ sol, float* __restrict__ out) {
  __shared__ float k1t[25600];   // [d][n]
  __shared__ float at[1600];     // attn [h][n]
  __shared__ float mhal[128];
  __shared__ float lg[200];
  __shared__ float qv[128];
  __shared__ int   bci;

  const int b = blockIdx.x, t = threadIdx.x;
  const int lane = t & 63, wave = t >> 6;
  const int o = t >> 3, q8 = t & 7;
  const int m4 = t >> 2, j4 = t & 3;
  const float* outb = OUT + (long)b * 200 * 512;

  // K1 -> LDS (transpose to [d][n], conflict-free reads later)
  for (int k = 0; k < 25; ++k) {
    int f = k * 1024 + t;
    int n = f >> 7, d = f & 127;
    k1t[d * 200 + n] = outb[n * 512 + d];
  }
  // V in regs: thread (o, q8) holds V[q8*25+i][o]
  float vreg[25];
  #pragma unroll
  for (int i = 0; i < 25; ++i) vreg[i] = outb[(q8 * 25 + i) * 512 + 128 + o];
  // U in regs, pre-rotated so all per-step indices are compile-time constant
  float ureg[32];
  if (t < 800) {
    #pragma unroll
    for (int ii = 0; ii < 32; ++ii) {
      int i = (ii + j4 * 8) & 31;
      ureg[ii] = outb[m4 * 512 + 256 + j4 * 32 + i];
    }
  }
  if (t < 128) qv[t] = QI[b * 128 + t];   // step-0 query

  int mk = 0;        // per-lane mask bits (node = lane + 64k), waves 0-7
  bool cm = false;   // node m4 masked, threads < 800
  bool live = true, picked0 = false;
  float llsum = 0.f, chose = 0.f;

  __syncthreads();

  for (int st = 0; st < 200; ++st) {
    // ---- A: scores + softmax (wave h = head h) ----
    if (wave < 8) {
      float q16[16];
      #pragma unroll
      for (int d = 0; d < 16; ++d) q16[d] = qv[wave * 16 + d];
      float sv[4];
      float mx = -INFINITY;
      #pragma unroll
      for (int k = 0; k < 4; ++k) {
        int n = lane + 64 * k;
        float s = -INFINITY;
        if (n < 200) {
          float a = 0.f;
          #pragma unroll
          for (int d = 0; d < 16; ++d)
            a += q16[d] * k1t[(wave * 16 + d) * 200 + n];
          s = a * 0.25f;
          if (mk & (1 << k)) s = NEGV;
        }
        sv[k] = s;
        mx = fmaxf(mx, s);
      }
      float vmax = wave_max(mx);
      float ls = 0.f;
      #pragma unroll
      for (int k = 0; k < 4; ++k) { sv[k] = expf(sv[k] - vmax); ls += sv[k]; }
      ls = wave_sum(ls);
      #pragma unroll
      for (int k = 0; k < 4; ++k) {
        int n = lane + 64 * k;
        if (n < 200) at[wave * 200 + n] = sv[k] / ls;
      }
    }
    __syncthreads();

    // ---- B: mha[o] = sum_n attn[h][n] * V[n][o] ----
    {
      const int h2 = t >> 7;
      float a = 0.f;
      #pragma unroll
      for (int i = 0; i < 25; ++i) a += at[h2 * 200 + q8 * 25 + i] * vreg[i];
      a += DPPF(a, 0xB1, 0.f);    // ^1 quad_perm
      a += DPPF(a, 0x4E, 0.f);    // ^2 quad_perm
      a += DPPF(a, 0x141, 0.f);   // row_half_mirror: other quad's sum
      if (q8 == 0) mhal[o] = a;
    }
    __syncthreads();

    // ---- C: logits[m] = 10*tanh((mha·U[m]) / sqrt(128)) ----
    if (t < 800) {
      float a = 0.f;
      #pragma unroll
      for (int ii = 0; ii < 32; ++ii)
        a += mhal[j4 * 32 + ((ii + j4 * 8) & 31)] * ureg[ii];
      a += DPPF(a, 0xB1, 0.f);
      a += DPPF(a, 0x4E, 0.f);
      if (j4 == 0) {
        float l = 10.f * tanhf(a / 11.313708498984761f);
        lg[m4] = cm ? NEGV : l;
      }
    }
    __syncthreads();

    // ---- D: argmax -> issue q-row load -> lse (overlaps load) ----
    if (wave < 8) {
      float lv[4];
      float mx = -INFINITY;
      #pragma unroll
      for (int k = 0; k < 4; ++k) {
        int n = lane + 64 * k;
        lv[k] = (n < 200) ? lg[n] : -INFINITY;
        mx = fmaxf(mx, lv[k]);
      }
      float vmax = wave_max(mx);
      int bidx = -1;
      #pragma unroll
      for (int k = 0; k < 4; ++k) {
        unsigned long long bm =
            __ballot((lane + 64 * k < 200) && (lv[k] == vmax));
        if (bidx < 0 && bm != 0ull) bidx = k * 64 + (int)__builtin_ctzll(bm);
      }
      int nxt = live ? bidx : 0;
      // dependent q-row load issued ASAP; lse math below hides some latency
      if (t < 128) qv[t] = outb[(long)nxt * 512 + 384 + t];
      float e = 0.f;
      #pragma unroll
      for (int k = 0; k < 4; ++k) e += expf(lv[k] - vmax);
      float se_ = wave_sum(e);
      float lse = logf(se_);
      if (t == 0) {
        chose = live ? (-lse) : ((lv[0] - vmax) - lse);  // lv[0]=lg[0] on lane0
        out[2048 + (long)b * 200 + st] = (float)nxt;
        bci = nxt;
      }
    }
    __syncthreads();

    int nxt = bci;
    if (!live) {
      // frozen: all remaining steps bit-identical
      if (t == 0) llsum += chose * (float)(200 - st);
      for (int s2 = st + 1 + t; s2 < 200; s2 += 1024)
        out[2048 + (long)b * 200 + s2] = 0.f;
      break;
    }
    if (t == 0) llsum += chose;
    if (wave < 8 && (nxt & 63) == lane) mk |= 1 << (nxt >> 6);
    if (t < 800 && nxt == m4) cm = true;
    if (nxt == 0) { live = false; picked0 = true; }
  }

  if (t == 0) out[1536 + b] = picked0 ? llsum : 0.f;
  if (t < 800 && j4 == 0) {
    float s = (m4 == 0) ? 1.f : ((picked0 && cm) ? 1.f : 0.f);
    sol[(long)b * 200 + m4] = s;
  }
}

// ---------------- cost ----------------
__global__ __launch_bounds__(256)
void cost_kernel(const float* __restrict__ x, const float* __restrict__ rf,
                 const float* __restrict__ sol, float* __restrict__ out) {
  __shared__ float solL[256];
  __shared__ float red[8];
  const int b = blockIdx.x, t = threadIdx.x;
  solL[t] = (t < 200) ? sol[b * 200 + t] : 0.f;
  __syncthreads();
  const float* x0 = x + (long)b * 40000;
  const float* x1 = x + 20480000l + (long)b * 40000;
  float a1 = 0.f, a2 = 0.f;
  if (t < 200) {
    for (int i = 0; i < 200; ++i) {
      if (solL[i] != 0.f) {
        a1 += x0[i * 200 + t];
        a2 += x1[i * 200 + t];
      }
    }
    float w = solL[t];
    a1 *= w; a2 *= w;
  }
  #pragma unroll
  for (int off = 32; off > 0; off >>= 1) {
    a1 += __shfl_xor(a1, off);
    a2 += __shfl_xor(a2, off);
  }
  if ((t & 63) == 0) { red[(t >> 6) * 2] = a1; red[(t >> 6) * 2 + 1] = a2; }
  __syncthreads();
  if (t == 0) {
    float f1 = red[0] + red[2] + red[4] + red[6];
    float f2 = red[1] + red[3] + red[5] + red[7];
    out[b]        = -(f1 * rf[0] + f2 * rf[1]);
    out[512 + b]  = f1;
    out[1024 + b] = f2;
  }
}

extern "C" void kernel_launch(void* const* d_in, const int* in_sizes, int n_in,
                              void* d_out, int out_size, void* d_ws, size_t ws_size,
                              hipStream_t stream) {
  const float* x     = (const float*)d_in[0];
  const float* rf    = (const float*)d_in[1];
  const float* emb   = (const float*)d_in[2];
  const float* Wk1   = (const float*)d_in[4];
  const float* bk1   = (const float*)d_in[5];
  const float* Wv    = (const float*)d_in[6];
  const float* Wk2   = (const float*)d_in[7];
  const float* Wout  = (const float*)d_in[8];
  const float* Wq    = (const float*)d_in[9];
  const float* initn = (const float*)d_in[10];
  float* out = (float*)d_out;
  float* ws  = (float*)d_ws;

  if (ws_size < (size_t)WS_FLOATS * 4) return;

  float* OUTb = ws + OUT_F;
  float* Mb   = ws + M_F;
  float* QRb  = ws + QR_F;
  float* QIb  = ws + QI_F;
  float* solb = ws + SOL_F;

  build_M<<<256, 256, 0, stream>>>(Wk1, Wv, Wk2, Wout, Wq, Mb);
  build_Q<<<256, 256, 0, stream>>>(rf, Wq, initn, QRb, QIb);
  gemm_static<<<12800, 256, 0, stream>>>(emb, Mb, bk1, QRb, OUTb);
  decode<<<512, 1024, 0, stream>>>(OUTb, QIb, solb, out);
  cost_kernel<<<512, 256, 0, stream>>>(x, rf, solb, out);
}

// Round 5
// 2799.996 us; speedup vs baseline: 1.4314x; 1.0014x over previous
//
#include <hip/hip_runtime.h>
#include <math.h>

#define NEGV (-1e9f)

// ws layout (float offsets):
//   OUT [B*N][512] : cols 0..127 K1, 128..255 V, 256..383 U=K2@Wout,
//                    384..511 Qfull = QR + emb@Wq[:,2:]^T  (QR folded in GEMM)
//   M   [128][512], QR [B][128], QI [B][128], SOL [B][200]
#define OUT_F   0l
#define M_F     52428800l
#define QR_F    (M_F + 65536l)
#define QI_F    (QR_F + 65536l)
#define SOL_F   (QI_F + 65536l)
#define WS_FLOATS (SOL_F + 102400l)   // 52,727,808 floats = ~211 MB (known OK)

// ---------------- DPP cross-lane helpers ----------------
#define DPPF(x, ctrl, oldv) __int_as_float(__builtin_amdgcn_update_dpp( \
      __float_as_int(oldv), __float_as_int(x), ctrl, 0xF, 0xF, false))

// full-wave max, exact (order-free), broadcast via readlane 63
__device__ __forceinline__ float wave_max(float x) {
  x = fmaxf(x, DPPF(x, 0x111, -INFINITY));   // row_shr:1
  x = fmaxf(x, DPPF(x, 0x112, -INFINITY));   // row_shr:2
  x = fmaxf(x, DPPF(x, 0x114, -INFINITY));   // row_shr:4
  x = fmaxf(x, DPPF(x, 0x118, -INFINITY));   // row_shr:8
  x = fmaxf(x, DPPF(x, 0x142, -INFINITY));   // row_bcast:15
  x = fmaxf(x, DPPF(x, 0x143, -INFINITY));   // row_bcast:31
  return __int_as_float(__builtin_amdgcn_readlane(__float_as_int(x), 63));
}
// full-wave sum (reassociated; decisions robust per round-1/4 evidence)
__device__ __forceinline__ float wave_sum(float x) {
  x = x + DPPF(x, 0x111, 0.f);
  x = x + DPPF(x, 0x112, 0.f);
  x = x + DPPF(x, 0x114, 0.f);
  x = x + DPPF(x, 0x118, 0.f);
  x = x + DPPF(x, 0x142, 0.f);
  x = x + DPPF(x, 0x143, 0.f);
  return __int_as_float(__builtin_amdgcn_readlane(__float_as_int(x), 63));
}

// ---------------- static precompute ----------------
__global__ __launch_bounds__(256)
void build_M(const float* __restrict__ Wk1, const float* __restrict__ Wv,
             const float* __restrict__ Wk2, const float* __restrict__ Wout,
             const float* __restrict__ Wq, float* __restrict__ Mbuf) {
  int g = blockIdx.x * 256 + threadIdx.x;
  int j = g >> 9, c = g & 511;
  float val;
  if (c < 128) {
    val = Wk1[c * 128 + j];
  } else if (c < 256) {
    val = Wv[(c - 128) * 128 + j];
  } else if (c < 384) {
    int d = c - 256;
    float s = 0.f;
    for (int e = 0; e < 128; ++e) s += Wk2[e * 128 + j] * Wout[e * 128 + d];
    val = s;
  } else {
    val = Wq[(c - 384) * 130 + 2 + j];
  }
  Mbuf[j * 512 + c] = val;
}

__global__ __launch_bounds__(256)
void build_Q(const float* __restrict__ rf, const float* __restrict__ Wq,
             const float* __restrict__ initn, float* __restrict__ QR,
             float* __restrict__ QI) {
  int g = blockIdx.x * 256 + threadIdx.x;   // 65536 = 512*128
  int b = g >> 7, d = g & 127;
  float qr = Wq[d * 130 + 0] * rf[b * 2 + 0] + Wq[d * 130 + 1] * rf[b * 2 + 1];
  float qi = qr;
  for (int j = 0; j < 128; ++j) qi += Wq[d * 130 + 2 + j] * initn[j];
  QR[g] = qr;
  QI[g] = qi;
}

// OUT[r][c] = emb[r]·M[:,c] (+bias c<128; +QR[b] for c>=384 -> full q rows)
__global__ __launch_bounds__(256)
void gemm_static(const float* __restrict__ emb, const float* __restrict__ Mbuf,
                 const float* __restrict__ bk1, const float* __restrict__ QR,
                 float* __restrict__ OUT) {
  int bid = blockIdx.x;                 // 1600 row-tiles * 8 col-tiles
  int rt = bid >> 3, ct = bid & 7;
  int r0 = rt * 64, c0 = ct * 64;
  int t = threadIdx.x, ty = t >> 4, tx = t & 15;
  int row0 = r0 + ty * 4;
  int col  = c0 + tx * 4;
  float acc[4][4] = {};
  const float* mp = Mbuf + col;
  for (int kb = 0; kb < 32; ++kb) {
    int k = kb * 4;
    float4 b0 = *(const float4*)(mp + (long)(k + 0) * 512);
    float4 b1 = *(const float4*)(mp + (long)(k + 1) * 512);
    float4 b2 = *(const float4*)(mp + (long)(k + 2) * 512);
    float4 b3 = *(const float4*)(mp + (long)(k + 3) * 512);
    float bm[4][4] = {{b0.x,b0.y,b0.z,b0.w},{b1.x,b1.y,b1.z,b1.w},
                      {b2.x,b2.y,b2.z,b2.w},{b3.x,b3.y,b3.z,b3.w}};
    #pragma unroll
    for (int rr = 0; rr < 4; ++rr) {
      float4 a4 = *(const float4*)(emb + (long)(row0 + rr) * 128 + k);
      float av[4] = {a4.x, a4.y, a4.z, a4.w};
      #pragma unroll
      for (int i = 0; i < 4; ++i)
        #pragma unroll
        for (int cc = 0; cc < 4; ++cc)
          acc[rr][cc] += av[i] * bm[i][cc];
    }
  }
  float badd[4] = {0.f, 0.f, 0.f, 0.f};
  if (c0 < 128) {
    #pragma unroll
    for (int cc = 0; cc < 4; ++cc) badd[cc] = bk1[col + cc];
  }
  #pragma unroll
  for (int rr = 0; rr < 4; ++rr) {
    int row = row0 + rr;
    float v[4];
    #pragma unroll
    for (int cc = 0; cc < 4; ++cc) v[cc] = acc[rr][cc] + badd[cc];
    if (col >= 384) {                   // fold QR -> full q rows
      int bb = row / 200;
      #pragma unroll
      for (int cc = 0; cc < 4; ++cc) v[cc] += QR[bb * 128 + (col - 384) + cc];
    }
    float4 v4; v4.x = v[0]; v4.y = v[1]; v4.z = v[2]; v4.w = v[3];
    *(float4*)(OUT + (long)row * 512 + col) = v4;
  }
}

// ---------------- decode: 1 block/batch, 4 barriers/step ----------------
// waves_per_eu(4,4): LDS already caps us at 1 block/CU (= 4 waves/EU), so
// clamping the occupancy TARGET to 4 raises the VGPR budget to 128 and
// keeps vreg/ureg in registers (round-4 spilled at the default 64-VGPR target).
__global__ __launch_bounds__(1024)
__attribute__((amdgpu_waves_per_eu(4, 4), amdgpu_flat_work_group_size(1024, 1024)))
void decode(const float* __restrict__ OUT, const float* __restrict__ QI,
            float* __restrict__ sol, float* __restrict__ out) {
  __shared__ float k1t[25600];   // [d][n]
  __shared__ float at[1600];     // attn [h][n]
  __shared__ float mhal[128];
  __shared__ float lg[200];
  __shared__ float qv[128];
  __shared__ int   bci;

  const int b = blockIdx.x, t = threadIdx.x;
  const int lane = t & 63, wave = t >> 6;
  const int o = t >> 3, q8 = t & 7;
  const int m4 = t >> 2, j4 = t & 3;
  const float* outb = OUT + (long)b * 200 * 512;

  // K1 -> LDS (transpose to [d][n], conflict-free reads later)
  for (int k = 0; k < 25; ++k) {
    int f = k * 1024 + t;
    int n = f >> 7, d = f & 127;
    k1t[d * 200 + n] = outb[n * 512 + d];
  }
  // V in regs: thread (o, q8) holds V[q8*25+i][o]
  float vreg[25];
  #pragma unroll
  for (int i = 0; i < 25; ++i) vreg[i] = outb[(q8 * 25 + i) * 512 + 128 + o];
  // U in regs, pre-rotated so all per-step indices are compile-time constant
  float ureg[32];
  if (t < 800) {
    #pragma unroll
    for (int ii = 0; ii < 32; ++ii) {
      int i = (ii + j4 * 8) & 31;
      ureg[ii] = outb[m4 * 512 + 256 + j4 * 32 + i];
    }
  }
  if (t < 128) qv[t] = QI[b * 128 + t];   // step-0 query

  int mk = 0;        // per-lane mask bits (node = lane + 64k), waves 0-7
  bool cm = false;   // node m4 masked, threads < 800
  bool live = true, picked0 = false;
  float llsum = 0.f, chose = 0.f;

  __syncthreads();

  for (int st = 0; st < 200; ++st) {
    // ---- A: scores + softmax (wave h = head h) ----
    if (wave < 8) {
      float q16[16];
      #pragma unroll
      for (int d = 0; d < 16; ++d) q16[d] = qv[wave * 16 + d];
      float sv[4];
      float mx = -INFINITY;
      #pragma unroll
      for (int k = 0; k < 4; ++k) {
        int n = lane + 64 * k;
        float s = -INFINITY;
        if (n < 200) {
          float a = 0.f;
          #pragma unroll
          for (int d = 0; d < 16; ++d)
            a += q16[d] * k1t[(wave * 16 + d) * 200 + n];
          s = a * 0.25f;
          if (mk & (1 << k)) s = NEGV;
        }
        sv[k] = s;
        mx = fmaxf(mx, s);
      }
      float vmax = wave_max(mx);
      float ls = 0.f;
      #pragma unroll
      for (int k = 0; k < 4; ++k) { sv[k] = expf(sv[k] - vmax); ls += sv[k]; }
      ls = wave_sum(ls);
      #pragma unroll
      for (int k = 0; k < 4; ++k) {
        int n = lane + 64 * k;
        if (n < 200) at[wave * 200 + n] = sv[k] / ls;
      }
    }
    __syncthreads();

    // ---- B: mha[o] = sum_n attn[h][n] * V[n][o] ----
    {
      const int h2 = t >> 7;
      float a = 0.f;
      #pragma unroll
      for (int i = 0; i < 25; ++i) a += at[h2 * 200 + q8 * 25 + i] * vreg[i];
      a += DPPF(a, 0xB1, 0.f);    // ^1 quad_perm
      a += DPPF(a, 0x4E, 0.f);    // ^2 quad_perm
      a += DPPF(a, 0x141, 0.f);   // row_half_mirror: other quad's sum
      if (q8 == 0) mhal[o] = a;
    }
    __syncthreads();

    // ---- C: logits[m] = 10*tanh((mha·U[m]) / sqrt(128)) ----
    if (t < 800) {
      float a = 0.f;
      #pragma unroll
      for (int ii = 0; ii < 32; ++ii)
        a += mhal[j4 * 32 + ((ii + j4 * 8) & 31)] * ureg[ii];
      a += DPPF(a, 0xB1, 0.f);
      a += DPPF(a, 0x4E, 0.f);
      if (j4 == 0) {
        float l = 10.f * tanhf(a / 11.313708498984761f);
        lg[m4] = cm ? NEGV : l;
      }
    }
    __syncthreads();

    // ---- D: argmax -> issue q-row load -> lse (overlaps load) ----
    if (wave < 8) {
      float lv[4];
      float mx = -INFINITY;
      #pragma unroll
      for (int k = 0; k < 4; ++k) {
        int n = lane + 64 * k;
        lv[k] = (n < 200) ? lg[n] : -INFINITY;
        mx = fmaxf(mx, lv[k]);
      }
      float vmax = wave_max(mx);
      int bidx = -1;
      #pragma unroll
      for (int k = 0; k < 4; ++k) {
        unsigned long long bm =
            __ballot((lane + 64 * k < 200) && (lv[k] == vmax));
        if (bidx < 0 && bm != 0ull) bidx = k * 64 + (int)__builtin_ctzll(bm);
      }
      int nxt = live ? bidx : 0;
      // dependent q-row load issued ASAP; lse math below hides some latency
      if (t < 128) qv[t] = outb[(long)nxt * 512 + 384 + t];
      float e = 0.f;
      #pragma unroll
      for (int k = 0; k < 4; ++k) e += expf(lv[k] - vmax);
      float se_ = wave_sum(e);
      float lse = logf(se_);
      if (t == 0) {
        chose = live ? (-lse) : ((lv[0] - vmax) - lse);  // lv[0]=lg[0] on lane0
        out[2048 + (long)b * 200 + st] = (float)nxt;
        bci = nxt;
      }
    }
    __syncthreads();

    int nxt = bci;
    if (!live) {
      // frozen: all remaining steps bit-identical
      if (t == 0) llsum += chose * (float)(200 - st);
      for (int s2 = st + 1 + t; s2 < 200; s2 += 1024)
        out[2048 + (long)b * 200 + s2] = 0.f;
      break;
    }
    if (t == 0) llsum += chose;
    if (wave < 8 && (nxt & 63) == lane) mk |= 1 << (nxt >> 6);
    if (t < 800 && nxt == m4) cm = true;
    if (nxt == 0) { live = false; picked0 = true; }
  }

  if (t == 0) out[1536 + b] = picked0 ? llsum : 0.f;
  if (t < 800 && j4 == 0) {
    float s = (m4 == 0) ? 1.f : ((picked0 && cm) ? 1.f : 0.f);
    sol[(long)b * 200 + m4] = s;
  }
}

// ---------------- cost ----------------
__global__ __launch_bounds__(256)
void cost_kernel(const float* __restrict__ x, const float* __restrict__ rf,
                 const float* __restrict__ sol, float* __restrict__ out) {
  __shared__ float solL[256];
  __shared__ float red[8];
  const int b = blockIdx.x, t = threadIdx.x;
  solL[t] = (t < 200) ? sol[b * 200 + t] : 0.f;
  __syncthreads();
  const float* x0 = x + (long)b * 40000;
  const float* x1 = x + 20480000l + (long)b * 40000;
  float a1 = 0.f, a2 = 0.f;
  if (t < 200) {
    for (int i = 0; i < 200; ++i) {
      if (solL[i] != 0.f) {
        a1 += x0[i * 200 + t];
        a2 += x1[i * 200 + t];
      }
    }
    float w = solL[t];
    a1 *= w; a2 *= w;
  }
  #pragma unroll
  for (int off = 32; off > 0; off >>= 1) {
    a1 += __shfl_xor(a1, off);
    a2 += __shfl_xor(a2, off);
  }
  if ((t & 63) == 0) { red[(t >> 6) * 2] = a1; red[(t >> 6) * 2 + 1] = a2; }
  __syncthreads();
  if (t == 0) {
    float f1 = red[0] + red[2] + red[4] + red[6];
    float f2 = red[1] + red[3] + red[5] + red[7];
    out[b]        = -(f1 * rf[0] + f2 * rf[1]);
    out[512 + b]  = f1;
    out[1024 + b] = f2;
  }
}

extern "C" void kernel_launch(void* const* d_in, const int* in_sizes, int n_in,
                              void* d_out, int out_size, void* d_ws, size_t ws_size,
                              hipStream_t stream) {
  const float* x     = (const float*)d_in[0];
  const float* rf    = (const float*)d_in[1];
  const float* emb   = (const float*)d_in[2];
  const float* Wk1   = (const float*)d_in[4];
  const float* bk1   = (const float*)d_in[5];
  const float* Wv    = (const float*)d_in[6];
  const float* Wk2   = (const float*)d_in[7];
  const float* Wout  = (const float*)d_in[8];
  const float* Wq    = (const float*)d_in[9];
  const float* initn = (const float*)d_in[10];
  float* out = (float*)d_out;
  float* ws  = (float*)d_ws;

  if (ws_size < (size_t)WS_FLOATS * 4) return;

  float* OUTb = ws + OUT_F;
  float* Mb   = ws + M_F;
  float* QRb  = ws + QR_F;
  float* QIb  = ws + QI_F;
  float* solb = ws + SOL_F;

  build_M<<<256, 256, 0, stream>>>(Wk1, Wv, Wk2, Wout, Wq, Mb);
  build_Q<<<256, 256, 0, stream>>>(rf, Wq, initn, QRb, QIb);
  gemm_static<<<12800, 256, 0, stream>>>(emb, Mb, bk1, QRb, OUTb);
  decode<<<512, 1024, 0, stream>>>(OUTb, QIb, solb, out);
  cost_kernel<<<512, 256, 0, stream>>>(x, rf, solb, out);
}

// Round 6
// 2034.141 us; speedup vs baseline: 1.9704x; 1.3765x over previous
//
#include <hip/hip_runtime.h>
#include <math.h>

#define NEGV (-1e9f)

// ws layout (float offsets):
//   OUT [B*N][512] : cols 0..127 K1, 128..255 V, 256..383 U=K2@Wout,
//                    384..511 Qfull = QR + emb@Wq[:,2:]^T  (QR folded in GEMM)
//   M   [128][512], QR [B][128] (dead after gemm -> reused as work counter),
//   QI  [B][128], SOL [B][200]
#define OUT_F   0l
#define M_F     52428800l
#define QR_F    (M_F + 65536l)
#define QI_F    (QR_F + 65536l)
#define SOL_F   (QI_F + 65536l)
#define WS_FLOATS (SOL_F + 102400l)   // 52,727,808 floats = ~211 MB (known OK)

typedef float f32x4 __attribute__((ext_vector_type(4)));

// ---------------- DPP cross-lane helpers ----------------
#define DPPF(x, ctrl, oldv) __int_as_float(__builtin_amdgcn_update_dpp( \
      __float_as_int(oldv), __float_as_int(x), ctrl, 0xF, 0xF, false))

__device__ __forceinline__ float wave_max(float x) {
  x = fmaxf(x, DPPF(x, 0x111, -INFINITY));   // row_shr:1
  x = fmaxf(x, DPPF(x, 0x112, -INFINITY));   // row_shr:2
  x = fmaxf(x, DPPF(x, 0x114, -INFINITY));   // row_shr:4
  x = fmaxf(x, DPPF(x, 0x118, -INFINITY));   // row_shr:8
  x = fmaxf(x, DPPF(x, 0x142, -INFINITY));   // row_bcast:15
  x = fmaxf(x, DPPF(x, 0x143, -INFINITY));   // row_bcast:31
  return __int_as_float(__builtin_amdgcn_readlane(__float_as_int(x), 63));
}
__device__ __forceinline__ float wave_sum(float x) {
  x = x + DPPF(x, 0x111, 0.f);
  x = x + DPPF(x, 0x112, 0.f);
  x = x + DPPF(x, 0x114, 0.f);
  x = x + DPPF(x, 0x118, 0.f);
  x = x + DPPF(x, 0x142, 0.f);
  x = x + DPPF(x, 0x143, 0.f);
  return __int_as_float(__builtin_amdgcn_readlane(__float_as_int(x), 63));
}

// ---------------- static precompute ----------------
__global__ __launch_bounds__(256)
void build_M(const float* __restrict__ Wk1, const float* __restrict__ Wv,
             const float* __restrict__ Wk2, const float* __restrict__ Wout,
             const float* __restrict__ Wq, float* __restrict__ Mbuf) {
  int g = blockIdx.x * 256 + threadIdx.x;
  int j = g >> 9, c = g & 511;
  float val;
  if (c < 128) {
    val = Wk1[c * 128 + j];
  } else if (c < 256) {
    val = Wv[(c - 128) * 128 + j];
  } else if (c < 384) {
    int d = c - 256;
    float s = 0.f;
    for (int e = 0; e < 128; ++e) s += Wk2[e * 128 + j] * Wout[e * 128 + d];
    val = s;
  } else {
    val = Wq[(c - 384) * 130 + 2 + j];
  }
  Mbuf[j * 512 + c] = val;
}

__global__ __launch_bounds__(256)
void build_Q(const float* __restrict__ rf, const float* __restrict__ Wq,
             const float* __restrict__ initn, float* __restrict__ QR,
             float* __restrict__ QI) {
  int g = blockIdx.x * 256 + threadIdx.x;   // 65536 = 512*128
  int b = g >> 7, d = g & 127;
  float qr = Wq[d * 130 + 0] * rf[b * 2 + 0] + Wq[d * 130 + 1] * rf[b * 2 + 1];
  float qi = qr;
  for (int j = 0; j < 128; ++j) qi += Wq[d * 130 + 2 + j] * initn[j];
  QR[g] = qr;
  QI[g] = qi;
}

__global__ __launch_bounds__(256)
void gemm_static(const float* __restrict__ emb, const float* __restrict__ Mbuf,
                 const float* __restrict__ bk1, const float* __restrict__ QR,
                 float* __restrict__ OUT) {
  int bid = blockIdx.x;                 // 1600 row-tiles * 8 col-tiles
  int rt = bid >> 3, ct = bid & 7;
  int r0 = rt * 64, c0 = ct * 64;
  int t = threadIdx.x, ty = t >> 4, tx = t & 15;
  int row0 = r0 + ty * 4;
  int col  = c0 + tx * 4;
  float acc[4][4] = {};
  const float* mp = Mbuf + col;
  for (int kb = 0; kb < 32; ++kb) {
    int k = kb * 4;
    float4 b0 = *(const float4*)(mp + (long)(k + 0) * 512);
    float4 b1 = *(const float4*)(mp + (long)(k + 1) * 512);
    float4 b2 = *(const float4*)(mp + (long)(k + 2) * 512);
    float4 b3 = *(const float4*)(mp + (long)(k + 3) * 512);
    float bm[4][4] = {{b0.x,b0.y,b0.z,b0.w},{b1.x,b1.y,b1.z,b1.w},
                      {b2.x,b2.y,b2.z,b2.w},{b3.x,b3.y,b3.z,b3.w}};
    #pragma unroll
    for (int rr = 0; rr < 4; ++rr) {
      float4 a4 = *(const float4*)(emb + (long)(row0 + rr) * 128 + k);
      float av[4] = {a4.x, a4.y, a4.z, a4.w};
      #pragma unroll
      for (int i = 0; i < 4; ++i)
        #pragma unroll
        for (int cc = 0; cc < 4; ++cc)
          acc[rr][cc] += av[i] * bm[i][cc];
    }
  }
  float badd[4] = {0.f, 0.f, 0.f, 0.f};
  if (c0 < 128) {
    #pragma unroll
    for (int cc = 0; cc < 4; ++cc) badd[cc] = bk1[col + cc];
  }
  #pragma unroll
  for (int rr = 0; rr < 4; ++rr) {
    int row = row0 + rr;
    float v[4];
    #pragma unroll
    for (int cc = 0; cc < 4; ++cc) v[cc] = acc[rr][cc] + badd[cc];
    if (col >= 384) {                   // fold QR -> full q rows
      int bb = row / 200;
      #pragma unroll
      for (int cc = 0; cc < 4; ++cc) v[cc] += QR[bb * 128 + (col - 384) + cc];
    }
    float4 v4; v4.x = v[0]; v4.y = v[1]; v4.z = v[2]; v4.w = v[3];
    *(float4*)(OUT + (long)row * 512 + col) = v4;
  }
}

__global__ void init_ctr(int* __restrict__ c) { *c = 0; }

// ---------------- decode: persistent work-stealing, register-forced ----------------
// No __launch_bounds__ (it suppressed waves_per_eu in rounds 4/5); the attrs
// alone set FWGS=1024 and clamp occupancy to 4 waves/EU -> 128-VGPR budget.
// V/U are ext_vector SSA values: register-allocated or nothing.
__global__
__attribute__((amdgpu_flat_work_group_size(1024, 1024), amdgpu_waves_per_eu(4, 4)))
void decode(const float* __restrict__ OUT, const float* __restrict__ QI,
            int* __restrict__ ctr, float* __restrict__ sol,
            float* __restrict__ out) {
  __shared__ float k1t[25600];                 // [d][n]
  __shared__ float at[1600];                   // attn [h][n]
  __shared__ __align__(16) float mhal[128];
  __shared__ float lg[200];
  __shared__ float qv[128];
  __shared__ int   bci;
  __shared__ int   bsel;

  const int t = threadIdx.x;
  const int lane = t & 63, wave = t >> 6;
  const int o = t >> 3, q8 = t & 7;
  const int m4 = t >> 2, j4 = t & 3;

  for (;;) {
    if (t == 0) bsel = atomicAdd(ctr, 1);
    __syncthreads();
    const int b = bsel;
    if (b >= 512) break;
    const float* outb = OUT + (long)b * 200 * 512;

    // K1 -> LDS (transpose to [d][n], conflict-free reads later)
    for (int k = 0; k < 25; ++k) {
      int f = k * 1024 + t;
      int n = f >> 7, d = f & 127;
      k1t[d * 200 + n] = outb[n * 512 + d];
    }
    // V: thread (o, q8) holds V[q8*25+i][o], i<25, as SSA vectors
    f32x4 vr0 = {}, vr1 = {}, vr2 = {}, vr3 = {}, vr4 = {}, vr5 = {};
    float v24;
    {
      const float* vp = outb + 128 + o;
      #pragma unroll
      for (int e = 0; e < 4; ++e) vr0[e] = vp[(q8 * 25 + e) * 512];
      #pragma unroll
      for (int e = 0; e < 4; ++e) vr1[e] = vp[(q8 * 25 + 4 + e) * 512];
      #pragma unroll
      for (int e = 0; e < 4; ++e) vr2[e] = vp[(q8 * 25 + 8 + e) * 512];
      #pragma unroll
      for (int e = 0; e < 4; ++e) vr3[e] = vp[(q8 * 25 + 12 + e) * 512];
      #pragma unroll
      for (int e = 0; e < 4; ++e) vr4[e] = vp[(q8 * 25 + 16 + e) * 512];
      #pragma unroll
      for (int e = 0; e < 4; ++e) vr5[e] = vp[(q8 * 25 + 20 + e) * 512];
      v24 = vp[(q8 * 25 + 24) * 512];
    }
    // U: thread (m4, j4) holds U[m4][j4*32..+31] as 8 chunk-rotated vectors:
    // uc[c] = U-chunk[(c + 2*j4)&7]  (same rotation as old (ii+j4*8)&31)
    f32x4 uc[8];
    if (t < 800) {
      const float* up = outb + m4 * 512 + 256 + j4 * 32;
      #pragma unroll
      for (int c = 0; c < 8; ++c)
        uc[c] = *(const f32x4*)(up + 4 * ((c + 2 * j4) & 7));
    } else {
      #pragma unroll
      for (int c = 0; c < 8; ++c) uc[c] = f32x4{};
    }
    if (t < 128) qv[t] = QI[b * 128 + t];   // step-0 query

    int mk = 0;        // per-lane mask bits (node = lane + 64k), waves 0-7
    bool cm = false;   // node m4 masked, threads < 800
    bool live = true, picked0 = false;
    float llsum = 0.f, chose = 0.f;

    __syncthreads();

    for (int st = 0; st < 200; ++st) {
      // ---- A: scores + softmax (wave h = head h) ----
      if (wave < 8) {
        float q16[16];
        #pragma unroll
        for (int d = 0; d < 16; ++d) q16[d] = qv[wave * 16 + d];
        float sv[4];
        float mx = -INFINITY;
        #pragma unroll
        for (int k = 0; k < 4; ++k) {
          int n = lane + 64 * k;
          float s = -INFINITY;
          if (n < 200) {
            float a = 0.f;
            #pragma unroll
            for (int d = 0; d < 16; ++d)
              a += q16[d] * k1t[(wave * 16 + d) * 200 + n];
            s = a * 0.25f;
            if (mk & (1 << k)) s = NEGV;
          }
          sv[k] = s;
          mx = fmaxf(mx, s);
        }
        float vmax = wave_max(mx);
        float ls = 0.f;
        #pragma unroll
        for (int k = 0; k < 4; ++k) { sv[k] = expf(sv[k] - vmax); ls += sv[k]; }
        ls = wave_sum(ls);
        #pragma unroll
        for (int k = 0; k < 4; ++k) {
          int n = lane + 64 * k;
          if (n < 200) at[wave * 200 + n] = sv[k] / ls;
        }
      }
      __syncthreads();

      // ---- B: mha[o] = sum_n attn[h][n] * V[n][o]  (i ascending, as before) ----
      {
        const int h2 = t >> 7;
        const float* ap = at + h2 * 200 + q8 * 25;
        float a = 0.f;
        #pragma unroll
        for (int e = 0; e < 4; ++e) a += ap[e] * vr0[e];
        #pragma unroll
        for (int e = 0; e < 4; ++e) a += ap[4 + e] * vr1[e];
        #pragma unroll
        for (int e = 0; e < 4; ++e) a += ap[8 + e] * vr2[e];
        #pragma unroll
        for (int e = 0; e < 4; ++e) a += ap[12 + e] * vr3[e];
        #pragma unroll
        for (int e = 0; e < 4; ++e) a += ap[16 + e] * vr4[e];
        #pragma unroll
        for (int e = 0; e < 4; ++e) a += ap[20 + e] * vr5[e];
        a += ap[24] * v24;
        a += DPPF(a, 0xB1, 0.f);    // ^1 quad_perm
        a += DPPF(a, 0x4E, 0.f);    // ^2 quad_perm
        a += DPPF(a, 0x141, 0.f);   // row_half_mirror: partner quad's sum
        if (q8 == 0) mhal[o] = a;
      }
      __syncthreads();

      // ---- C: logits[m] = 10*tanh((mha . U[m]) / sqrt(128)) ----
      if (t < 800) {
        float a = 0.f;
        #pragma unroll
        for (int c = 0; c < 8; ++c) {
          int q = (c + 2 * j4) & 7;
          f32x4 mh = *(const f32x4*)(&mhal[j4 * 32 + q * 4]);
          #pragma unroll
          for (int e = 0; e < 4; ++e) a += mh[e] * uc[c][e];
        }
        a += DPPF(a, 0xB1, 0.f);
        a += DPPF(a, 0x4E, 0.f);
        if (j4 == 0) {
          float l = 10.f * tanhf(a / 11.313708498984761f);
          lg[m4] = cm ? NEGV : l;
        }
      }
      __syncthreads();

      // ---- D: argmax -> issue q-row load -> lse (overlaps load) ----
      if (wave < 8) {
        float lv[4];
        float mx = -INFINITY;
        #pragma unroll
        for (int k = 0; k < 4; ++k) {
          int n = lane + 64 * k;
          lv[k] = (n < 200) ? lg[n] : -INFINITY;
          mx = fmaxf(mx, lv[k]);
        }
        float vmax = wave_max(mx);
        int bidx = -1;
        #pragma unroll
        for (int k = 0; k < 4; ++k) {
          unsigned long long bm =
              __ballot((lane + 64 * k < 200) && (lv[k] == vmax));
          if (bidx < 0 && bm != 0ull) bidx = k * 64 + (int)__builtin_ctzll(bm);
        }
        int nxt = live ? bidx : 0;
        if (t < 128) qv[t] = outb[(long)nxt * 512 + 384 + t];
        float e = 0.f;
        #pragma unroll
        for (int k = 0; k < 4; ++k) e += expf(lv[k] - vmax);
        float se_ = wave_sum(e);
        float lse = logf(se_);
        if (t == 0) {
          chose = live ? (-lse) : ((lv[0] - vmax) - lse);
          out[2048 + (long)b * 200 + st] = (float)nxt;
          bci = nxt;
        }
      }
      __syncthreads();

      int nxt = bci;
      if (!live) {
        if (t == 0) llsum += chose * (float)(200 - st);
        for (int s2 = st + 1 + t; s2 < 200; s2 += 1024)
          out[2048 + (long)b * 200 + s2] = 0.f;
        break;
      }
      if (t == 0) llsum += chose;
      if (wave < 8 && (nxt & 63) == lane) mk |= 1 << (nxt >> 6);
      if (t < 800 && nxt == m4) cm = true;
      if (nxt == 0) { live = false; picked0 = true; }
    }

    if (t == 0) out[1536 + b] = picked0 ? llsum : 0.f;
    if (t < 800 && j4 == 0) {
      float s = (m4 == 0) ? 1.f : ((picked0 && cm) ? 1.f : 0.f);
      sol[(long)b * 200 + m4] = s;
    }
    __syncthreads();   // protect LDS reuse before next grab
  }
}

// ---------------- cost ----------------
__global__ __launch_bounds__(256)
void cost_kernel(const float* __restrict__ x, const float* __restrict__ rf,
                 const float* __restrict__ sol, float* __restrict__ out) {
  __shared__ float solL[256];
  __shared__ float red[8];
  const int b = blockIdx.x, t = threadIdx.x;
  solL[t] = (t < 200) ? sol[b * 200 + t] : 0.f;
  __syncthreads();
  const float* x0 = x + (long)b * 40000;
  const float* x1 = x + 20480000l + (long)b * 40000;
  float a1 = 0.f, a2 = 0.f;
  if (t < 200) {
    for (int i = 0; i < 200; ++i) {
      if (solL[i] != 0.f) {
        a1 += x0[i * 200 + t];
        a2 += x1[i * 200 + t];
      }
    }
    float w = solL[t];
    a1 *= w; a2 *= w;
  }
  #pragma unroll
  for (int off = 32; off > 0; off >>= 1) {
    a1 += __shfl_xor(a1, off);
    a2 += __shfl_xor(a2, off);
  }
  if ((t & 63) == 0) { red[(t >> 6) * 2] = a1; red[(t >> 6) * 2 + 1] = a2; }
  __syncthreads();
  if (t == 0) {
    float f1 = red[0] + red[2] + red[4] + red[6];
    float f2 = red[1] + red[3] + red[5] + red[7];
    out[b]        = -(f1 * rf[0] + f2 * rf[1]);
    out[512 + b]  = f1;
    out[1024 + b] = f2;
  }
}

extern "C" void kernel_launch(void* const* d_in, const int* in_sizes, int n_in,
                              void* d_out, int out_size, void* d_ws, size_t ws_size,
                              hipStream_t stream) {
  const float* x     = (const float*)d_in[0];
  const float* rf    = (const float*)d_in[1];
  const float* emb   = (const float*)d_in[2];
  const float* Wk1   = (const float*)d_in[4];
  const float* bk1   = (const float*)d_in[5];
  const float* Wv    = (const float*)d_in[6];
  const float* Wk2   = (const float*)d_in[7];
  const float* Wout  = (const float*)d_in[8];
  const float* Wq    = (const float*)d_in[9];
  const float* initn = (const float*)d_in[10];
  float* out = (float*)d_out;
  float* ws  = (float*)d_ws;

  if (ws_size < (size_t)WS_FLOATS * 4) return;

  float* OUTb = ws + OUT_F;
  float* Mb   = ws + M_F;
  float* QRb  = ws + QR_F;   // dead after gemm; first 4 bytes reused as counter
  float* QIb  = ws + QI_F;
  float* solb = ws + SOL_F;

  build_M<<<256, 256, 0, stream>>>(Wk1, Wv, Wk2, Wout, Wq, Mb);
  build_Q<<<256, 256, 0, stream>>>(rf, Wq, initn, QRb, QIb);
  gemm_static<<<12800, 256, 0, stream>>>(emb, Mb, bk1, QRb, OUTb);
  init_ctr<<<1, 1, 0, stream>>>((int*)QRb);
  decode<<<256, 1024, 0, stream>>>(OUTb, QIb, (int*)QRb, solb, out);
  cost_kernel<<<512, 256, 0, stream>>>(x, rf, solb, out);
}